// Round 1
// 419.760 us; speedup vs baseline: 1.0002x; 1.0002x over previous
//
#include <hip/hip_runtime.h>

#define MAXDEG 192
#define NEG_SLOPE 0.2f
#define D 128

__device__ __forceinline__ float bf2f(unsigned short u) {
    return __uint_as_float(((unsigned)u) << 16);
}
__device__ __forceinline__ unsigned short f2bf(float f) {
    unsigned u = __float_as_uint(f);
    return (unsigned short)((u + 0x7fffu + ((u >> 16) & 1u)) >> 16);
}
__device__ __forceinline__ unsigned pack2bf(float x, float y) {
    return (unsigned)f2bf(x) | ((unsigned)f2bf(y) << 16);
}
// dtype detect: adj[0,0]==1.0 guaranteed (self-loop). f32 -> 0x3F800000.
__device__ __forceinline__ int is_f32(const void* adj) {
    return ((const unsigned*)adj)[0] == 0x3F800000u;
}

// --------------------------------------------------------------------------
// ELL compaction of one 4-row group (wave per row). Ballot-based stream
// compaction: no atomics, no LDS, no barriers, wave-uniform running count.
// Order within a row is arbitrary (softmax+sum are order-invariant).
// --------------------------------------------------------------------------
__device__ __forceinline__ void ell_group(
        int g, const void* __restrict__ adj, int N, int f32m,
        unsigned short* __restrict__ cols, int* __restrict__ deg) {
    const int w = threadIdx.x >> 6, lane = threadIdx.x & 63;
    const int row = g * 4 + w;
    unsigned short* crow = cols + (size_t)row * MAXDEG;
    const unsigned long long lt = (1ull << lane) - 1ull;
    int cnt = 0;  // wave-uniform (ballot/popc results are uniform)
    if (f32m) {
        const float4* arow = (const float4*)((const float*)adj + (size_t)row * N);
        const int nv = N / 4;
        for (int c = lane; c < nv; c += 128) {
            float4 u0 = arow[c];
            float4 u1 = arow[c + 64];
            const unsigned* a0 = (const unsigned*)&u0;
            const unsigned* a1 = (const unsigned*)&u1;
            #pragma unroll
            for (int e = 0; e < 4; e++) {
                unsigned long long m = __ballot(a0[e] != 0u);
                if (a0[e]) {
                    int p = cnt + __popcll(m & lt);
                    if (p < MAXDEG) crow[p] = (unsigned short)(c * 4 + e);
                }
                cnt += __popcll(m);
            }
            #pragma unroll
            for (int e = 0; e < 4; e++) {
                unsigned long long m = __ballot(a1[e] != 0u);
                if (a1[e]) {
                    int p = cnt + __popcll(m & lt);
                    if (p < MAXDEG) crow[p] = (unsigned short)((c + 64) * 4 + e);
                }
                cnt += __popcll(m);
            }
        }
    } else {
        const uint4* arow = (const uint4*)((const unsigned short*)adj + (size_t)row * N);
        const int nv = N / 8;
        for (int c = lane; c < nv; c += 128) {
            uint4 u0 = arow[c];
            uint4 u1 = arow[c + 64];
            const unsigned short* s0 = (const unsigned short*)&u0;
            const unsigned short* s1 = (const unsigned short*)&u1;
            #pragma unroll
            for (int e = 0; e < 8; e++) {
                unsigned long long m = __ballot(s0[e] != 0);
                if (s0[e]) {
                    int p = cnt + __popcll(m & lt);
                    if (p < MAXDEG) crow[p] = (unsigned short)(c * 8 + e);
                }
                cnt += __popcll(m);
            }
            #pragma unroll
            for (int e = 0; e < 8; e++) {
                unsigned long long m = __ballot(s1[e] != 0);
                if (s1[e]) {
                    int p = cnt + __popcll(m & lt);
                    if (p < MAXDEG) crow[p] = (unsigned short)((c + 64) * 8 + e);
                }
                cnt += __popcll(m);
            }
        }
    }
    if (lane == 0) deg[row] = cnt < MAXDEG ? cnt : MAXDEG;
}

// --------------------------------------------------------------------------
// 32x128 tile of H = A @ W (K=128), H written as bf16. Fused score epilogue
// (scores from f32 accumulators, so bf16 H costs no score accuracy).
// smem: xs=[0,4096) f32, ws=[4096,8192) f32.
// --------------------------------------------------------------------------
__device__ __forceinline__ void gemm_tile32(
        int t, const void* __restrict__ A, const void* __restrict__ W,
        int aF, int f32m, const void* __restrict__ attS, const void* __restrict__ attD,
        unsigned short* __restrict__ Hb, float* __restrict__ asrc, float* __restrict__ adst,
        float* __restrict__ smem) {
    float* xs = smem;
    float* ws = smem + 4096;
    const int tid = threadIdx.x;
    const size_t row0 = (size_t)t * 32;

    if (aF) {
        const float4* av = (const float4*)((const float*)A + row0 * D);
        float4* xl = (float4*)xs;
        #pragma unroll
        for (int k = 0; k < 4; k++) xl[tid + 256 * k] = av[tid + 256 * k];
    } else {
        const uint4* av = (const uint4*)((const unsigned short*)A + row0 * D);
        #pragma unroll
        for (int k = 0; k < 2; k++) {
            uint4 u = av[tid + 256 * k];
            const unsigned short* us = (const unsigned short*)&u;
            #pragma unroll
            for (int e = 0; e < 8; e++) xs[(tid + 256 * k) * 8 + e] = bf2f(us[e]);
        }
    }

    const int tx = tid & 31, ty = tid >> 5;
    const int c0 = tx * 4, r0 = ty * 4;
    float acc[4][4] = {};
    for (int p = 0; p < 4; p++) {
        __syncthreads();
        if (f32m) {
            const float4* wv = (const float4*)((const float*)W + (size_t)p * 32 * D);
            float4* wl = (float4*)ws;
            #pragma unroll
            for (int k = 0; k < 4; k++) wl[tid + 256 * k] = wv[tid + 256 * k];
        } else {
            const uint4* wv = (const uint4*)((const unsigned short*)W + (size_t)p * 32 * D);
            #pragma unroll
            for (int k = 0; k < 2; k++) {
                uint4 u = wv[tid + 256 * k];
                const unsigned short* us = (const unsigned short*)&u;
                #pragma unroll
                for (int e = 0; e < 8; e++) ws[(tid + 256 * k) * 8 + e] = bf2f(us[e]);
            }
        }
        __syncthreads();
        #pragma unroll 8
        for (int k = 0; k < 32; k++) {
            float4 wv = *(const float4*)&ws[k * D + c0];
            #pragma unroll
            for (int i = 0; i < 4; i++) {
                float xv = xs[(r0 + i) * D + p * 32 + k];
                acc[i][0] += xv * wv.x; acc[i][1] += xv * wv.y;
                acc[i][2] += xv * wv.z; acc[i][3] += xv * wv.w;
            }
        }
    }
    // bf16 H store (8 B per thread-row)
    #pragma unroll
    for (int i = 0; i < 4; i++) {
        ushort4 hv;
        hv.x = f2bf(acc[i][0]); hv.y = f2bf(acc[i][1]);
        hv.z = f2bf(acc[i][2]); hv.w = f2bf(acc[i][3]);
        *(ushort4*)&Hb[(row0 + r0 + i) * D + c0] = hv;
    }

    float aSv[4], aDv[4];
    #pragma unroll
    for (int j = 0; j < 4; j++) {
        aSv[j] = f32m ? ((const float*)attS)[c0 + j] : bf2f(((const unsigned short*)attS)[c0 + j]);
        aDv[j] = f32m ? ((const float*)attD)[c0 + j] : bf2f(((const unsigned short*)attD)[c0 + j]);
    }
    #pragma unroll
    for (int i = 0; i < 4; i++) {
        float s = acc[i][0] * aSv[0] + acc[i][1] * aSv[1] + acc[i][2] * aSv[2] + acc[i][3] * aSv[3];
        float d = acc[i][0] * aDv[0] + acc[i][1] * aDv[1] + acc[i][2] * aDv[2] + acc[i][3] * aDv[3];
        #pragma unroll
        for (int off = 16; off > 0; off >>= 1) {
            s += __shfl_down(s, off, 32);
            d += __shfl_down(d, off, 32);
        }
        if (tx == 0) {
            asrc[row0 + r0 + i] = s;
            adst[row0 + r0 + i] = d;
        }
    }
}

// --------------------------------------------------------------------------
// Wave-local softmax + split-wave bf16 gather for one row.
// Softmax phase: all 64 lanes (3 slots each). Gather phase: lanes 0-31 take
// even ELL slots, lanes 32-63 odd slots; each lane loads uint2 (4 channels,
// 8 B) so one load instruction covers TWO neighbors. Halves merged with
// __shfl_xor(32). Returns channels [4*(lane&31), +4), bias added, opt. relu;
// valid on all lanes — caller stores from lanes 0-31.
// --------------------------------------------------------------------------
__device__ __forceinline__ float4 agg_row_bf(
        const unsigned short* __restrict__ Hb,
        const float* __restrict__ asrc, float ai,
        const unsigned short* __restrict__ crow, int d,
        const void* __restrict__ bias, int f32m, int relu,
        float* __restrict__ scn, unsigned short* __restrict__ sjj, int lane) {
    const int s0 = lane, s1 = lane + 64, s2 = lane + 128;
    unsigned short j0 = 0, j1 = 0, j2 = 0;
    float e0 = -3e38f, e1 = -3e38f, e2 = -3e38f;
    if (s0 < d) { j0 = crow[s0]; float e = asrc[j0] + ai; e0 = (e >= 0.f) ? e : NEG_SLOPE * e; }
    if (s1 < d) { j1 = crow[s1]; float e = asrc[j1] + ai; e1 = (e >= 0.f) ? e : NEG_SLOPE * e; }
    if (s2 < d) { j2 = crow[s2]; float e = asrc[j2] + ai; e2 = (e >= 0.f) ? e : NEG_SLOPE * e; }
    float m = fmaxf(e0, fmaxf(e1, e2));
    #pragma unroll
    for (int off = 1; off < 64; off <<= 1) m = fmaxf(m, __shfl_xor(m, off));
    float p0 = (s0 < d) ? __expf(e0 - m) : 0.f;
    float p1 = (s1 < d) ? __expf(e1 - m) : 0.f;
    float p2 = (s2 < d) ? __expf(e2 - m) : 0.f;
    float l = p0 + p1 + p2;
    #pragma unroll
    for (int off = 1; off < 64; off <<= 1) l += __shfl_xor(l, off);
    const float invl = 1.f / l;
    scn[s0] = p0 * invl; sjj[s0] = j0;
    scn[s1] = p1 * invl; sjj[s1] = j1;
    scn[s2] = p2 * invl; sjj[s2] = j2;
    // same-wave LDS RAW: no block barrier needed

    const int half = lane >> 5, hl = lane & 31;
    const uint2* H4 = (const uint2*)Hb;  // row j = 32 x uint2 (4 bf16 each)
    float a0 = 0.f, a1 = 0.f, a2 = 0.f, a3 = 0.f;
    int k = 0;
    for (; k + 15 < d; k += 16) {
        unsigned jj[8]; float ww[8]; uint2 vv[8];
        #pragma unroll
        for (int u = 0; u < 8; u++) {
            const int slot = k + 2 * u + half;
            jj[u] = sjj[slot]; ww[u] = scn[slot];
        }
        #pragma unroll
        for (int u = 0; u < 8; u++) vv[u] = H4[jj[u] * 32u + (unsigned)hl];
        #pragma unroll
        for (int u = 0; u < 8; u++) {
            a0 += ww[u] * bf2f((unsigned short)(vv[u].x & 0xffffu));
            a1 += ww[u] * bf2f((unsigned short)(vv[u].x >> 16));
            a2 += ww[u] * bf2f((unsigned short)(vv[u].y & 0xffffu));
            a3 += ww[u] * bf2f((unsigned short)(vv[u].y >> 16));
        }
    }
    for (int s = k + half; s < d; s += 2) {
        const unsigned j = sjj[s];
        const float wk = scn[s];
        uint2 v = H4[j * 32u + (unsigned)hl];
        a0 += wk * bf2f((unsigned short)(v.x & 0xffffu));
        a1 += wk * bf2f((unsigned short)(v.x >> 16));
        a2 += wk * bf2f((unsigned short)(v.y & 0xffffu));
        a3 += wk * bf2f((unsigned short)(v.y >> 16));
    }
    a0 += __shfl_xor(a0, 32);
    a1 += __shfl_xor(a1, 32);
    a2 += __shfl_xor(a2, 32);
    a3 += __shfl_xor(a3, 32);

    float4 r;
    if (f32m) {
        float4 b = ((const float4*)bias)[hl];
        r = make_float4(a0 + b.x, a1 + b.y, a2 + b.z, a3 + b.w);
    } else {
        uint2 b = ((const uint2*)bias)[hl];
        r = make_float4(a0 + bf2f((unsigned short)(b.x & 0xffffu)),
                        a1 + bf2f((unsigned short)(b.x >> 16)),
                        a2 + bf2f((unsigned short)(b.y & 0xffffu)),
                        a3 + bf2f((unsigned short)(b.y >> 16)));
    }
    if (relu) {
        r.x = fmaxf(r.x, 0.f); r.y = fmaxf(r.y, 0.f);
        r.z = fmaxf(r.z, 0.f); r.w = fmaxf(r.w, 0.f);
    }
    return r;
}

// --------------------------------------------------------------------------
// K1: blocks [0,GT) gemm layer0, blocks [GT, GT+N/4) ELL compaction.
// --------------------------------------------------------------------------
__global__ __launch_bounds__(256) void ell_gemm0(
        const void* __restrict__ x, const void* __restrict__ adj,
        const void* __restrict__ W0, const void* __restrict__ aS0,
        const void* __restrict__ aD0, int N,
        unsigned short* __restrict__ cols, int* __restrict__ deg,
        unsigned short* __restrict__ h, float* __restrict__ asrc, float* __restrict__ adst) {
    __shared__ float smem[8192]; // 32 KB (gemm path only)
    const int bid = blockIdx.x;
    const int f32m = is_f32(adj);
    const int GT = N / 32;
    if (bid < GT)
        gemm_tile32(bid, x, W0, f32m, f32m, aS0, aD0, h, asrc, adst, smem);
    else
        ell_group(bid - GT, adj, N, f32m, cols, deg);
}

// --------------------------------------------------------------------------
// K2: fused aggregate-layer0 + gemm-layer1 for 8 rows per block.
// Phase A: aggregate rows into LDS (f32) + write bf16/f32 out0 to d_out.
// Phase B: gemm those 8 rows with W1 from LDS tile, write bf16 h2 + scores.
// --------------------------------------------------------------------------
__global__ __launch_bounds__(256) void agg0_gemm1(
        const unsigned short* __restrict__ h,
        const float* __restrict__ asrc0, const float* __restrict__ adst0,
        const unsigned short* __restrict__ cols, const int* __restrict__ deg,
        const void* __restrict__ b0, const void* __restrict__ W1,
        const void* __restrict__ aS1, const void* __restrict__ aD1,
        const void* __restrict__ adjFlag, void* __restrict__ out,
        unsigned short* __restrict__ h2,
        float* __restrict__ asrc1, float* __restrict__ adst1, int N) {
    __shared__ float xs[8 * D];        // 4 KB: out0 rows f32
    __shared__ float wstage[32 * D];   // 16 KB
    __shared__ float scnA[4 * MAXDEG];
    __shared__ unsigned short sjjA[4 * MAXDEG];
    const int tid = threadIdx.x;
    const int w = tid >> 6, lane = tid & 63;
    const int f32m = is_f32(adjFlag);

    // ---- Phase A: aggregate 8 rows (2 passes x 4 waves)
    #pragma unroll
    for (int pass = 0; pass < 2; pass++) {
        const int rl = pass * 4 + w;
        const int row = blockIdx.x * 8 + rl;
        float4 v = agg_row_bf(h, asrc0, adst0[row],
                              cols + (size_t)row * MAXDEG, deg[row],
                              b0, f32m, 1,
                              scnA + w * MAXDEG, sjjA + w * MAXDEG, lane);
        if (lane < 32) {
            *(float4*)&xs[rl * D + 4 * lane] = v;
            if (f32m) ((float4*)out)[(size_t)row * 32 + lane] = v;
            else      ((uint2*)out)[(size_t)row * 32 + lane] =
                          make_uint2(pack2bf(v.x, v.y), pack2bf(v.z, v.w));
        }
    }

    // ---- Phase B: gemm 8x128 @ 128x128
    const int tx = tid & 31, ty = tid >> 5;
    const int c0 = tx * 4;
    float acc[4] = {};
    for (int p = 0; p < 4; p++) {
        __syncthreads(); // phase-A xs done (p=0) / previous wstage reads done
        if (f32m) {
            const float4* wv = (const float4*)((const float*)W1 + (size_t)p * 32 * D);
            float4* wl = (float4*)wstage;
            #pragma unroll
            for (int k = 0; k < 4; k++) wl[tid + 256 * k] = wv[tid + 256 * k];
        } else {
            const uint4* wv = (const uint4*)((const unsigned short*)W1 + (size_t)p * 32 * D);
            #pragma unroll
            for (int k = 0; k < 2; k++) {
                uint4 u = wv[tid + 256 * k];
                const unsigned short* us = (const unsigned short*)&u;
                #pragma unroll
                for (int e = 0; e < 8; e++) wstage[(tid + 256 * k) * 8 + e] = bf2f(us[e]);
            }
        }
        __syncthreads();
        #pragma unroll 8
        for (int k = 0; k < 32; k++) {
            float4 wv = *(const float4*)&wstage[k * D + c0];
            float xv = xs[ty * D + p * 32 + k];
            acc[0] += xv * wv.x; acc[1] += xv * wv.y;
            acc[2] += xv * wv.z; acc[3] += xv * wv.w;
        }
    }
    const size_t row1 = (size_t)blockIdx.x * 8 + ty;
    ushort4 hv;
    hv.x = f2bf(acc[0]); hv.y = f2bf(acc[1]); hv.z = f2bf(acc[2]); hv.w = f2bf(acc[3]);
    *(ushort4*)&h2[row1 * D + c0] = hv;

    float aSv[4], aDv[4];
    #pragma unroll
    for (int j = 0; j < 4; j++) {
        aSv[j] = f32m ? ((const float*)aS1)[c0 + j] : bf2f(((const unsigned short*)aS1)[c0 + j]);
        aDv[j] = f32m ? ((const float*)aD1)[c0 + j] : bf2f(((const unsigned short*)aD1)[c0 + j]);
    }
    float s = acc[0] * aSv[0] + acc[1] * aSv[1] + acc[2] * aSv[2] + acc[3] * aSv[3];
    float d = acc[0] * aDv[0] + acc[1] * aDv[1] + acc[2] * aDv[2] + acc[3] * aDv[3];
    #pragma unroll
    for (int off = 16; off > 0; off >>= 1) {
        s += __shfl_down(s, off, 32);
        d += __shfl_down(d, off, 32);
    }
    if (tx == 0) {
        asrc1[row1] = s;
        adst1[row1] = d;
    }
}

// --------------------------------------------------------------------------
// K3: aggregate layer1 (4 rows/block), final output.
// --------------------------------------------------------------------------
__global__ __launch_bounds__(256) void aggregate1(
        const unsigned short* __restrict__ h2,
        const float* __restrict__ asrc1, const float* __restrict__ adst1,
        const unsigned short* __restrict__ cols, const int* __restrict__ deg,
        const void* __restrict__ b1, const void* __restrict__ adjFlag,
        void* __restrict__ out, int N) {
    __shared__ float scnA[4 * MAXDEG];
    __shared__ unsigned short sjjA[4 * MAXDEG];
    const int w = threadIdx.x >> 6, lane = threadIdx.x & 63;
    const int row = blockIdx.x * 4 + w;
    const int f32m = is_f32(adjFlag);
    float4 v = agg_row_bf(h2, asrc1, adst1[row],
                          cols + (size_t)row * MAXDEG, deg[row],
                          b1, f32m, 0,
                          scnA + w * MAXDEG, sjjA + w * MAXDEG, lane);
    const size_t off4 = (size_t)N * 32;  // layer-1 offset in float4/uint2 units
    if (lane < 32) {
        if (f32m) ((float4*)out)[off4 + (size_t)row * 32 + lane] = v;
        else      ((uint2*)out)[off4 + (size_t)row * 32 + lane] =
                      make_uint2(pack2bf(v.x, v.y), pack2bf(v.z, v.w));
    }
}

// --------------------------------------------------------------------------
extern "C" void kernel_launch(void* const* d_in, const int* in_sizes, int n_in,
                              void* d_out, int out_size, void* d_ws, size_t ws_size,
                              hipStream_t stream) {
    const int N = in_sizes[0] / D; // 8192

    char* w = (char*)d_ws;
    int* deg             = (int*)w;            w += (size_t)N * sizeof(int);
    unsigned short* cols = (unsigned short*)w; w += (size_t)N * MAXDEG * sizeof(unsigned short);
    unsigned short* h    = (unsigned short*)w; w += (size_t)N * D * sizeof(unsigned short);
    unsigned short* h2   = (unsigned short*)w; w += (size_t)N * D * sizeof(unsigned short);
    float* asrc0         = (float*)w;          w += (size_t)N * sizeof(float);
    float* adst0         = (float*)w;          w += (size_t)N * sizeof(float);
    float* asrc1         = (float*)w;          w += (size_t)N * sizeof(float);
    float* adst1         = (float*)w;

    const void* adj = d_in[1];

    // K1: ELL build + gemm layer0 (independent work, fused)
    ell_gemm0<<<N / 32 + N / 4, 256, 0, stream>>>(
        d_in[0], adj, d_in[2], d_in[3], d_in[4], N, cols, deg, h, asrc0, adst0);

    // K2: aggregate layer0 + gemm layer1 (per-block row ownership)
    agg0_gemm1<<<N / 8, 256, 0, stream>>>(
        h, asrc0, adst0, cols, deg, d_in[5], d_in[6], d_in[7], d_in[8],
        adj, d_out, h2, asrc1, adst1, N);

    // K3: aggregate layer1 (final output)
    aggregate1<<<N / 4, 256, 0, stream>>>(
        h2, asrc1, adst1, cols, deg, d_in[9], adj, d_out, N);
}